// Round 13
// baseline (87.796 us; speedup 1.0000x reference)
//
#include <hip/hip_runtime.h>

typedef __attribute__((ext_vector_type(8))) short bf16x8;
typedef __attribute__((ext_vector_type(4))) float f32x4;
typedef __attribute__((ext_vector_type(16))) float f32x16;
typedef __attribute__((ext_vector_type(8))) unsigned short us8;
typedef unsigned short u16;
typedef unsigned int u32;

__device__ inline u16 f2bf(float f) {
  union { float f; unsigned u; } v; v.f = f;
  unsigned r = v.u + 0x7FFFu + ((v.u >> 16) & 1u);  // RNE
  return (u16)(r >> 16);
}

__device__ inline u32 cvtpk_bf16(float lo, float hi) {
  u32 r;
  asm volatile("v_cvt_pk_bf16_f32 %0, %1, %2" : "=v"(r) : "v"(lo), "v"(hi));
  return r;
}

__device__ inline void gload_lds16(const void* g, void* l) {
  __builtin_amdgcn_global_load_lds(
      (const __attribute__((address_space(1))) void*)g,
      (__attribute__((address_space(3))) void*)l, 16, 0, 0);
}

// T12: one 32-krow P^T subtile (16 f32) -> two bf16x8 B-fragments (verified R3+)
__device__ inline void p_to_pf(const f32x16& p, bf16x8& f0, bf16x8& f1) {
  union { u32 u[4]; bf16x8 v; } fr;
  u32 a = cvtpk_bf16(p[0], p[1]),   c = cvtpk_bf16(p[2], p[3]);
  u32 b = cvtpk_bf16(p[4], p[5]),   d = cvtpk_bf16(p[6], p[7]);
  asm volatile("v_permlane32_swap_b32 %0, %1" : "+v"(a), "+v"(b));
  asm volatile("v_permlane32_swap_b32 %0, %1" : "+v"(c), "+v"(d));
  fr.u[0] = a; fr.u[1] = c; fr.u[2] = b; fr.u[3] = d;  f0 = fr.v;
  u32 a2 = cvtpk_bf16(p[8], p[9]),   c2 = cvtpk_bf16(p[10], p[11]);
  u32 b2 = cvtpk_bf16(p[12], p[13]), d2 = cvtpk_bf16(p[14], p[15]);
  asm volatile("v_permlane32_swap_b32 %0, %1" : "+v"(a2), "+v"(b2));
  asm volatile("v_permlane32_swap_b32 %0, %1" : "+v"(c2), "+v"(d2));
  fr.u[0] = a2; fr.u[1] = c2; fr.u[2] = b2; fr.u[3] = d2;  f1 = fr.v;
}

// ---------------- fused convert f32 -> bf16 (x, Wq, Wk, Wv in one launch) ----------------
__global__ void cvt_all(const float* __restrict__ x, const float* __restrict__ wq,
                        const float* __restrict__ wk, const float* __restrict__ wv,
                        u16* __restrict__ out) {
  int i = (blockIdx.x * blockDim.x + threadIdx.x) * 4;
  const float* src; int off;
  if (i < 4194304)      { src = x;  off = 0; }
  else if (i < 5242880) { src = wq; off = 4194304; }
  else if (i < 6291456) { src = wk; off = 5242880; }
  else                  { src = wv; off = 6291456; }
  float4 v = *reinterpret_cast<const float4*>(src + (i - off));
  ushort4 o;
  o.x = f2bf(v.x); o.y = f2bf(v.y); o.z = f2bf(v.z); o.w = f2bf(v.w);
  *reinterpret_cast<ushort4*>(out + i) = o;
}

// ---------------- QKV projection GEMM: out = x @ W.T + b ----------------
// z==0: Q (scaled, [bh][n][64]); z==1: K ([bh][n][64]); z==2: V TRANSPOSED ([bh][d][2048]).
__global__ __launch_bounds__(256, 3) void gemm_qkv(
    const u16* __restrict__ X,
    const u16* __restrict__ Wq, const u16* __restrict__ Wk, const u16* __restrict__ Wv,
    const float* __restrict__ bq, const float* __restrict__ bk, const float* __restrict__ bv,
    u16* __restrict__ Oq, u16* __restrict__ Ok, u16* __restrict__ Ovt)
{
  constexpr int GK = 1024;
  __shared__ __align__(16) u16 As[128 * 64];
  __shared__ __align__(16) u16 Bs[128 * 64];

  const int z = blockIdx.z;
  const u16* W = (z == 0) ? Wq : (z == 1) ? Wk : Wv;
  const float* bias = (z == 0) ? bq : (z == 1) ? bk : bv;
  const float scale = (z == 0) ? (1.4426950408889634f / 32.0f) : 1.0f;

  const int tid = threadIdx.x;
  const int lane = tid & 63, w = tid >> 6;
  const int wm = w >> 1, wn = w & 1;
  const int q = lane & 15, g = lane >> 4;
  const int bm0 = blockIdx.x * 128, bn0 = blockIdx.y * 128;

  int srow[4], sgc[4];
  #pragma unroll
  for (int i = 0; i < 4; ++i) {
    int c = i * 256 + tid;
    srow[i] = c >> 3;
    sgc[i] = (((c & 7) ^ ((c >> 3) & 7)) * 8);
  }

  f32x4 acc[4][4];
  #pragma unroll
  for (int i = 0; i < 4; ++i)
    #pragma unroll
    for (int j = 0; j < 4; ++j) acc[i][j] = (f32x4){0.f, 0.f, 0.f, 0.f};

  for (int k0 = 0; k0 < GK; k0 += 64) {
    #pragma unroll
    for (int i = 0; i < 4; ++i) {
      int c8 = (i * 256 + tid) * 8;
      gload_lds16(&X[(bm0 + srow[i]) * GK + k0 + sgc[i]], &As[c8]);
      gload_lds16(&W[(bn0 + srow[i]) * GK + k0 + sgc[i]], &Bs[c8]);
    }
    __syncthreads();

    #pragma unroll
    for (int kk = 0; kk < 2; ++kk) {
      bf16x8 af[4], bfr[4];
      #pragma unroll
      for (int mi = 0; mi < 4; ++mi) {
        int row = wm * 64 + mi * 16 + q;
        af[mi] = *reinterpret_cast<const bf16x8*>(
            &As[row * 64 + (((kk * 4 + g) ^ (row & 7)) * 8)]);
      }
      #pragma unroll
      for (int ni = 0; ni < 4; ++ni) {
        int row = wn * 64 + ni * 16 + q;
        bfr[ni] = *reinterpret_cast<const bf16x8*>(
            &Bs[row * 64 + (((kk * 4 + g) ^ (row & 7)) * 8)]);
      }
      #pragma unroll
      for (int mi = 0; mi < 4; ++mi)
        #pragma unroll
        for (int ni = 0; ni < 4; ++ni)
          acc[mi][ni] = __builtin_amdgcn_mfma_f32_16x16x32_bf16(af[mi], bfr[ni], acc[mi][ni], 0, 0, 0);
    }
    __syncthreads();
  }

  if (z == 2) {
    #pragma unroll
    for (int mi = 0; mi < 4; ++mi) {
      #pragma unroll
      for (int ni = 0; ni < 4; ++ni) {
        int col = bn0 + wn * 64 + ni * 16 + q;
        float bb = bias[col];
        int h = col >> 6, d = col & 63;
        int row0 = bm0 + wm * 64 + mi * 16 + 4 * g;
        int b = row0 >> 11, n0 = row0 & 2047;
        ushort4 o4;
        o4.x = f2bf(acc[mi][ni][0] + bb);
        o4.y = f2bf(acc[mi][ni][1] + bb);
        o4.z = f2bf(acc[mi][ni][2] + bb);
        o4.w = f2bf(acc[mi][ni][3] + bb);
        *reinterpret_cast<ushort4*>(&Ovt[(((b << 4) + h) * 64 + d) * 2048 + n0]) = o4;
      }
    }
  } else {
    u16* O = (z == 0) ? Oq : Ok;
    #pragma unroll
    for (int mi = 0; mi < 4; ++mi) {
      #pragma unroll
      for (int ni = 0; ni < 4; ++ni) {
        int col = bn0 + wn * 64 + ni * 16 + q;
        float bb = bias[col];
        int h = col >> 6, d = col & 63;
        #pragma unroll
        for (int r = 0; r < 4; ++r) {
          int row = bm0 + wm * 64 + mi * 16 + 4 * g + r;
          int b = row >> 11, n = row & 2047;
          float v = (acc[mi][ni][r] + bb) * scale;
          O[(((b << 4) + h) * 2048 + n) * 64 + d] = f2bf(v);
        }
      }
    }
  }
}

// ---------------- flash attention: BARRIER-FREE wave-private pipeline ----------------
// 4 waves/block. Waves 0-1: keys [0,1024) for q-rows [0,64)/[64,128); waves 2-3:
// keys [1024,2048) same q-rows. Each wave owns a PRIVATE 16KB LDS double-buffer
// (K[32][64] + V^T[64][32] per tile, KVBLK=32) staged by its own global_load_lds
// and guarded only by per-wave counted s_waitcnt vmcnt(8) -- NO __syncthreads in
// the main loop. Waves drift into complementary phases so MFMA / trans(exp2) /
// LDS pipes overlap instead of serializing. Work identical to R12 (same DMA
// bytes, same ds_read count, same MFMA/exp2 count) -- pure scheduling change.
// Static-max softmax => linear split-K combine (one barrier, after the loop).
__global__ __launch_bounds__(256, 2) void attn_kernel(
    const u16* __restrict__ Q, const u16* __restrict__ K, const u16* __restrict__ Vt,
    float* __restrict__ out)
{
  __shared__ __align__(16) u16 smem[32768];   // 64KB: 4 waves x 16KB private dbuf

  const int tid = threadIdx.x;
  const int lane = tid & 63, w = tid >> 6;          // 4 waves
  const int half = w >> 1, qw = w & 1;
  const int ql = lane & 31, h = lane >> 5, l7 = lane & 7;

  // XCD swizzle: xcd = lin&7 owns bh in [xcd*4, xcd*4+4)
  const int lin = blockIdx.x;
  const int xcd = lin & 7, li = lin >> 3;
  const int bh = xcd * 4 + (li >> 4);
  const int b = bh >> 4, hd = bh & 15;
  const int qrow0 = (li & 15) * 128 + qw * 64;      // this wave's 64 q-rows

  const u16* Qp = Q + (bh * 2048 + qrow0) * 64;
  const u16* Kp = K + (bh * 2048 + half * 1024) * 64;
  const u16* Vp = Vt + bh * 64 * 2048 + half * 1024;  // [64 d][2048 n]

  // Q fragments: qf[qh][ks], lane ql holds Q[qrow0 + qh*32 + ql][16ks + 8h + j]
  bf16x8 qf[2][4];
  #pragma unroll
  for (int qh = 0; qh < 2; ++qh)
    #pragma unroll
    for (int ks = 0; ks < 4; ++ks)
      qf[qh][ks] = *reinterpret_cast<const bf16x8*>(Qp + (qh * 32 + ql) * 64 + 16 * ks + 8 * h);

  // wave-private LDS: [buf][K 4KB | V 4KB]
  u16* wbase = smem + w * 8192;            // u16 units: 16KB = 8192 u16
  // staging geometry: 256 chunks (16B) per 4KB tile, 4 per lane.
  // K tile [32 rows][64 cols]: 8 chunks/row, swizzle XOR mod 8.
  // V tile [64 rows][32 cols]: 4 chunks/row, swizzle XOR mod 4.
  int krow_s[4], kcb_s[4], vrow_s[4], vcb_s[4];
  #pragma unroll
  for (int i = 0; i < 4; ++i) {
    int c = i * 64 + lane;
    krow_s[i] = c >> 3;
    kcb_s[i] = 16 * ((c & 7) ^ ((c >> 3) & 7));
    vrow_s[i] = c >> 2;
    vcb_s[i] = 16 * ((c & 3) ^ ((c >> 2) & 3));
  }

  f32x16 o00, o01, o10, o11;   // o[dt][qh]
  #pragma unroll
  for (int i = 0; i < 16; ++i) { o00[i] = 0.f; o01[i] = 0.f; o10[i] = 0.f; o11[i] = 0.f; }
  float ls0 = 0.0f, ls1 = 0.0f;

  // prologue: stage tile 0 into buf0 (no barrier -- wave-private)
  #pragma unroll
  for (int i = 0; i < 4; ++i)
    gload_lds16((const char*)(Kp + krow_s[i] * 64) + kcb_s[i], &wbase[i * 512]);
  #pragma unroll
  for (int i = 0; i < 4; ++i)
    gload_lds16((const char*)(Vp + vrow_s[i] * 2048) + vcb_s[i], &wbase[2048 + i * 512]);

  for (int t = 0; t < 32; ++t) {
    const int cur = t & 1, nxt = cur ^ 1;
    const int kb = t * 32;
    // issue next-tile DMA (8 ops); t==31 issues clamped dummy (uniform counts)
    const int kbn = (t < 31) ? (kb + 32) : kb;
    u16* nb = wbase + nxt * 4096;
    #pragma unroll
    for (int i = 0; i < 4; ++i)
      gload_lds16((const char*)(Kp + (kbn + krow_s[i]) * 64) + kcb_s[i], &nb[i * 512]);
    #pragma unroll
    for (int i = 0; i < 4; ++i)
      gload_lds16((const char*)(Vp + vrow_s[i] * 2048 + kbn) + vcb_s[i], &nb[2048 + i * 512]);

    // wait for THIS tile's 8 ops (8 newer remain in flight) -- per-wave, sound
    asm volatile("s_waitcnt vmcnt(8)" ::: "memory");
    __builtin_amdgcn_sched_barrier(0);

    const u16* kl = wbase + cur * 4096;         // K [32][64] swizzled
    const u16* vl = kl + 2048;                  // V^T [64][32] swizzled

    // ---- QK^T: p[qh] (32 krows x 32 q), 8 MFMA, 4 kf reads ----
    f32x16 p0, p1;
    #pragma unroll
    for (int i = 0; i < 16; ++i) { p0[i] = 0.f; p1[i] = 0.f; }
    __builtin_amdgcn_s_setprio(1);
    #pragma unroll
    for (int ks = 0; ks < 4; ++ks) {
      bf16x8 kf = *reinterpret_cast<const bf16x8*>(
          kl + ql * 64 + (((2 * ks + h) ^ (ql & 7)) * 8));
      p0 = __builtin_amdgcn_mfma_f32_32x32x16_bf16(kf, qf[0][ks], p0, 0, 0, 0);
      p1 = __builtin_amdgcn_mfma_f32_32x32x16_bf16(kf, qf[1][ks], p1, 0, 0, 0);
    }
    __builtin_amdgcn_s_setprio(0);

    // ---- hoisted V-frag reads (latency hides under softmax VALU) ----
    bf16x8 vf[2][2];   // [dt][kslice]
    #pragma unroll
    for (int dt = 0; dt < 2; ++dt)
      #pragma unroll
      for (int kss = 0; kss < 2; ++kss) {
        int r = dt * 32 + ql;
        vf[dt][kss] = *reinterpret_cast<const bf16x8*>(
            vl + r * 32 + (((2 * kss + h) ^ (r & 3)) * 8));
      }

    // ---- static-max softmax (log2 domain; Q pre-scaled by log2e/32) ----
    #pragma unroll
    for (int i = 0; i < 16; ++i) {
      p0[i] = __builtin_amdgcn_exp2f(p0[i]);
      p1[i] = __builtin_amdgcn_exp2f(p1[i]);
    }
    {
      float s0 = 0.f, s1 = 0.f;
      #pragma unroll
      for (int i = 0; i < 16; ++i) { s0 += p0[i]; s1 += p1[i]; }
      s0 += __shfl_xor(s0, 32);
      s1 += __shfl_xor(s1, 32);
      ls0 += s0; ls1 += s1;
    }

    // ---- P^T -> bf16 B-fragments ----
    bf16x8 pf0[2], pf1[2];   // [kslice] for qh 0/1
    p_to_pf(p0, pf0[0], pf0[1]);
    p_to_pf(p1, pf1[0], pf1[1]);

    // ---- PV: o[dt][qh] += V^T-slice @ P^T-slice, 8 MFMA ----
    __builtin_amdgcn_s_setprio(1);
    #pragma unroll
    for (int kss = 0; kss < 2; ++kss) {
      o00 = __builtin_amdgcn_mfma_f32_32x32x16_bf16(vf[0][kss], pf0[kss], o00, 0, 0, 0);
      o01 = __builtin_amdgcn_mfma_f32_32x32x16_bf16(vf[0][kss], pf1[kss], o01, 0, 0, 0);
      o10 = __builtin_amdgcn_mfma_f32_32x32x16_bf16(vf[1][kss], pf0[kss], o10, 0, 0, 0);
      o11 = __builtin_amdgcn_mfma_f32_32x32x16_bf16(vf[1][kss], pf1[kss], o11, 0, 0, 0);
    }
    __builtin_amdgcn_s_setprio(0);
    // NO barrier: next iteration's vmcnt(8) + program-order DS ops guard reuse.
  }

  // ---- combine key-halves in LDS (static-max => linear) ----
  __syncthreads();   // drains all DMA (incl. dummies) + all waves done
  float* Of = reinterpret_cast<float*>(smem);
  float* Lf = Of + 128 * 66;
  const int obase = (qw * 64 + lane) * 66;
  if (half == 1) {
    #pragma unroll
    for (int i = 0; i < 16; ++i) {
      Of[obase + i]      = o00[i];
      Of[obase + 16 + i] = o01[i];
      Of[obase + 32 + i] = o10[i];
      Of[obase + 48 + i] = o11[i];
    }
    Lf[qw * 64 + lane] = ls0;
    Lf[128 + qw * 64 + lane] = ls1;
  }
  __syncthreads();
  if (half == 0) {
    #pragma unroll
    for (int i = 0; i < 16; ++i) {
      o00[i] += Of[obase + i];
      o01[i] += Of[obase + 16 + i];
      o10[i] += Of[obase + 32 + i];
      o11[i] += Of[obase + 48 + i];
    }
    ls0 += Lf[qw * 64 + lane];
    ls1 += Lf[128 + qw * 64 + lane];

    float r0 = 1.0f / ls0, r1 = 1.0f / ls1;
    float* op0 = out + ((size_t)(b * 2048 + qrow0 + ql) * 1024 + hd * 64);
    float* op1 = out + ((size_t)(b * 2048 + qrow0 + 32 + ql) * 1024 + hd * 64);
    #pragma unroll
    for (int g2 = 0; g2 < 4; ++g2) {
      float4 v;
      v.x = o00[4 * g2 + 0] * r0; v.y = o00[4 * g2 + 1] * r0;
      v.z = o00[4 * g2 + 2] * r0; v.w = o00[4 * g2 + 3] * r0;
      *reinterpret_cast<float4*>(op0 + 8 * g2 + 4 * h) = v;
      v.x = o10[4 * g2 + 0] * r0; v.y = o10[4 * g2 + 1] * r0;
      v.z = o10[4 * g2 + 2] * r0; v.w = o10[4 * g2 + 3] * r0;
      *reinterpret_cast<float4*>(op0 + 32 + 8 * g2 + 4 * h) = v;
      v.x = o01[4 * g2 + 0] * r1; v.y = o01[4 * g2 + 1] * r1;
      v.z = o01[4 * g2 + 2] * r1; v.w = o01[4 * g2 + 3] * r1;
      *reinterpret_cast<float4*>(op1 + 8 * g2 + 4 * h) = v;
      v.x = o11[4 * g2 + 0] * r1; v.y = o11[4 * g2 + 1] * r1;
      v.z = o11[4 * g2 + 2] * r1; v.w = o11[4 * g2 + 3] * r1;
      *reinterpret_cast<float4*>(op1 + 32 + 8 * g2 + 4 * h) = v;
    }
  }
}

extern "C" void kernel_launch(void* const* d_in, const int* in_sizes, int n_in,
                              void* d_out, int out_size, void* d_ws, size_t ws_size,
                              hipStream_t stream) {
  const float* x  = (const float*)d_in[0];
  const float* Wq = (const float*)d_in[1];
  const float* bq = (const float*)d_in[2];
  const float* Wk = (const float*)d_in[3];
  const float* bk = (const float*)d_in[4];
  const float* Wv = (const float*)d_in[5];
  const float* bv = (const float*)d_in[6];
  float* out = (float*)d_out;

  u16* ws  = (u16*)d_ws;
  u16* xb  = ws;                  // 4096*1024
  u16* wqb = xb  + 4194304;       // 1024*1024
  u16* wkb = wqb + 1048576;
  u16* wvb = wkb + 1048576;
  u16* qb  = wvb + 1048576;       // [32][2048][64]
  u16* kb  = qb  + 4194304;
  u16* vt  = kb  + 4194304;       // [32][64][2048] (written transposed by gemm z==2)

  cvt_all<<<7168, 256, 0, stream>>>(x, Wq, Wk, Wv, ws);

  gemm_qkv<<<dim3(32, 8, 3), 256, 0, stream>>>(xb, wqb, wkb, wvb, bq, bk, bv, qb, kb, vt);

  attn_kernel<<<512, 256, 0, stream>>>(qb, kb, vt, out);
}